// Round 12
// baseline (50048.804 us; speedup 1.0000x reference)
//
#include <hip/hip_runtime.h>
#include <cstdint>

// DROP_MODE 3 = JAX partitionable threefry, bits = x0^x1  (VERIFIED r3+: absmax 0.0039)

static constexpr int TDEC = 400, TENC = 300, NMEL = 80;

__device__ __forceinline__ uint2 threefry2x32(uint32_t k0, uint32_t k1,
                                              uint32_t x0, uint32_t x1) {
  uint32_t k2 = k0 ^ k1 ^ 0x1BD11BDAu;
  x0 += k0; x1 += k1;
#define TFR(r) { x0 += x1; x1 = (x1 << (r)) | (x1 >> (32 - (r))); x1 ^= x0; }
  TFR(13) TFR(15) TFR(26) TFR(6)
  x0 += k1; x1 += k2 + 1u;
  TFR(17) TFR(29) TFR(16) TFR(24)
  x0 += k2; x1 += k0 + 2u;
  TFR(13) TFR(15) TFR(26) TFR(6)
  x0 += k0; x1 += k1 + 3u;
  TFR(17) TFR(29) TFR(16) TFR(24)
  x0 += k1; x1 += k2 + 4u;
  TFR(13) TFR(15) TFR(26) TFR(6)
  x0 += k2; x1 += k0 + 5u;
#undef TFR
  return make_uint2(x0, x1);
}

__device__ __forceinline__ bool keep_mask(uint32_t key0, uint32_t key1, uint32_t idx) {
  uint2 o = threefry2x32(key0, key1, 0u, idx);
  uint32_t bits = o.x ^ o.y;
  float u = __uint_as_float((bits >> 9) | 0x3f800000u) - 1.0f;
  return u < 0.5f;
}

__device__ __forceinline__ float dot4(float4 w, float4 a) {
  return w.x * a.x + w.y * a.y + w.z * a.z + w.w * a.w;
}
__device__ __forceinline__ float nt_load(const float* p) {
  return __builtin_nontemporal_load(p);
}

// ---- prenet (teacher-forced, all 400 steps parallel; verified) --------------
template <int K>
__device__ __forceinline__ void prenet_layer(const float* in_lds, float* out_lds,
                                             float* out_g, const float* __restrict__ W,
                                             uint32_t key0, uint32_t key1, int b0) {
  const int tid = threadIdx.x;
  const int cgp = tid & 63, bg = tid >> 6;
  float acc[4][4];
#pragma unroll
  for (int cc = 0; cc < 4; ++cc)
#pragma unroll
    for (int rr = 0; rr < 4; ++rr) acc[cc][rr] = 0.f;
  const float4* W4 = (const float4*)W;
  const float4* in4 = (const float4*)in_lds;
  for (int k4 = 0; k4 < K / 4; ++k4) {
    float4 a[4];
#pragma unroll
    for (int rr = 0; rr < 4; ++rr) a[rr] = in4[(bg * 4 + rr) * (K / 4) + k4];
#pragma unroll
    for (int cc = 0; cc < 4; ++cc) {
      float4 w = W4[(cgp + 64 * cc) * (K / 4) + k4];
#pragma unroll
      for (int rr = 0; rr < 4; ++rr) acc[cc][rr] += dot4(w, a[rr]);
    }
  }
#pragma unroll
  for (int cc = 0; cc < 4; ++cc)
#pragma unroll
    for (int rr = 0; rr < 4; ++rr) {
      int c = cgp + 64 * cc, br = bg * 4 + rr;
      float val = fmaxf(acc[cc][rr], 0.f);
      val = keep_mask(key0, key1, (uint32_t)((b0 + br) * 256 + c)) ? val * 2.f : 0.f;
      if (out_lds) out_lds[br * 256 + c] = val;
      if (out_g) out_g[(b0 + br) * 256 + c] = val;
    }
  __syncthreads();
}

__global__ __launch_bounds__(256) void prenet_kernel(const float* __restrict__ mels,
                                                     const float* __restrict__ Wp0,
                                                     const float* __restrict__ Wp1,
                                                     const float* __restrict__ Wp2,
                                                     float* __restrict__ x_all) {
  __shared__ float bufA[16 * 256];
  __shared__ float bufB[16 * 256];
  const int t = blockIdx.x >> 1, b0 = (blockIdx.x & 1) * 16;
  const int tid = threadIdx.x;
  for (int i = tid; i < 16 * 80; i += 256) {
    int br = i / 80, k = i % 80;
    bufB[br * 80 + k] = (t == 0) ? 0.f : mels[((b0 + br) * TDEC + (t - 1)) * NMEL + k];
  }
  __syncthreads();
  uint2 k0v = threefry2x32(0u, 42u, 0u, (uint32_t)(t * 3 + 0));
  uint2 k1v = threefry2x32(0u, 42u, 0u, (uint32_t)(t * 3 + 1));
  uint2 k2v = threefry2x32(0u, 42u, 0u, (uint32_t)(t * 3 + 2));
  prenet_layer<80>(bufB, bufA, nullptr, Wp0, k0v.x, k0v.y, b0);
  prenet_layer<256>(bufA, bufB, nullptr, Wp1, k1v.x, k1v.y, b0);
  prenet_layer<256>(bufB, nullptr, x_all + t * 8192, Wp2, k2v.x, k2v.y, b0);
}

// ---- pmem = enc @ Wm.T (verified) --------------------------------------------
__global__ __launch_bounds__(256) void pmem_kernel(const float* __restrict__ enc,
                                                   const float* __restrict__ Wm,
                                                   float* __restrict__ pmem) {
  const int b = blockIdx.x / 10, pc = blockIdx.x % 10;
  const int j = threadIdx.x & 127, ph = threadIdx.x >> 7;
  const float4* Wm4 = (const float4*)Wm;
  const float4* enc4 = (const float4*)enc + (size_t)(b * 300 + pc * 30 + ph * 15) * 128;
  float acc[15];
#pragma unroll
  for (int pp = 0; pp < 15; ++pp) acc[pp] = 0.f;
  for (int k4 = 0; k4 < 128; ++k4) {
    float4 w = Wm4[j * 128 + k4];
#pragma unroll
    for (int pp = 0; pp < 15; ++pp) acc[pp] += dot4(w, enc4[pp * 128 + k4]);
  }
#pragma unroll
  for (int pp = 0; pp < 15; ++pp)
    pmem[(size_t)(b * 300 + pc * 30 + ph * 15 + pp) * 128 + j] = acc[pp];
}

// ---- shared param block -------------------------------------------------------
struct GP {
  const float *xall, *enc, *pmem;
  const int* lens;
  const float *Wiha, *Whha, *biha, *bhha;
  const float *Wihd, *Whhd, *bihd, *bhhd;
  const float *Wq, *Kloc, *Wl, *vv, *Wout, *bout, *Wg, *bg;
  float *ah, *dh;        // [2][32][512] ping-pong
  float *e2;             // [2][32][304]
  float *pM, *pS;        // [2][32][4]
  float *V;              // [2][32*4][512]
  float *awsum2;         // [2][32][300]
  float *omel, *ogate, *oalign;
};

// ---- batched GRU slice (r3-verified math) ------------------------------------
template <int KIN>
__device__ __forceinline__ void gru_phase(const float4* __restrict__ A4, int a4n,
                                          const float4* B4,
                                          const float4* __restrict__ H4,
                                          const float* __restrict__ Wih,
                                          const float* __restrict__ Whh,
                                          const float* __restrict__ bih,
                                          const float* __restrict__ bhh,
                                          const float* __restrict__ hprev,
                                          float* __restrict__ hout,
                                          int idx0, float* lds) {
  const int tid = threadIdx.x;
  const int row = tid >> 3, seg = tid & 7;
  constexpr int K4I = KIN / 4;
  constexpr int SI = K4I / 8;
  const float4* Wih4 = (const float4*)Wih;
  const float4* Whh4 = (const float4*)Whh;
  float acc[24];
#pragma unroll
  for (int g = 0; g < 24; ++g) acc[g] = 0.f;
  for (int s = 0; s < SI; ++s) {
    int k4 = seg * SI + s;
    float4 a = (k4 < a4n) ? A4[row * a4n + k4] : B4[row * 128 + (k4 - a4n)];
#pragma unroll
    for (int gate = 0; gate < 3; ++gate)
#pragma unroll
      for (int i = 0; i < 4; ++i)
        acc[gate * 4 + i] += dot4(Wih4[(size_t)(gate * 512 + idx0 + i) * K4I + k4], a);
  }
  for (int s = 0; s < 16; ++s) {
    int k4 = seg * 16 + s;
    float4 a = H4[row * 128 + k4];
#pragma unroll
    for (int gate = 0; gate < 3; ++gate)
#pragma unroll
      for (int i = 0; i < 4; ++i)
        acc[12 + gate * 4 + i] += dot4(Whh4[(size_t)(gate * 512 + idx0 + i) * 128 + k4], a);
  }
#pragma unroll
  for (int g = 0; g < 24; ++g) lds[(g * 32 + row) * 8 + seg] = acc[g];
  __syncthreads();
  if (tid < 128) {
    int i = tid >> 5, r = tid & 31;
    float gi[3], gh[3];
#pragma unroll
    for (int gate = 0; gate < 3; ++gate) {
      float si = 0.f, sh = 0.f;
#pragma unroll
      for (int s = 0; s < 8; ++s) {
        si += lds[((gate * 4 + i) * 32 + r) * 8 + s];
        sh += lds[((12 + gate * 4 + i) * 32 + r) * 8 + s];
      }
      gi[gate] = si + bih[gate * 512 + idx0 + i];
      gh[gate] = sh + bhh[gate * 512 + idx0 + i];
    }
    float rr = 1.f / (1.f + expf(-(gi[0] + gh[0])));
    float zz = 1.f / (1.f + expf(-(gi[1] + gh[1])));
    float nn = tanhf(gi[2] + rr * gh[2]);
    float hp = hprev[r * 512 + idx0 + i];
    hout[r * 512 + idx0 + i] = (1.f - zz) * nn + zz * hp;
  }
}

// ---- K_G: ctx fixup staging + attGRU_t || decGRU_{t-1} -----------------------
__global__ __launch_bounds__(256) void k_gru(GP P, int t) {
  __shared__ float lds[6144];
  __shared__ float ctxS[16384];   // combined ctx_{t-1}[32][512]
  __shared__ float wqL[128];
  const int tid = threadIdx.x, blk = blockIdx.x;
  const int p0 = t & 1, p1 = p0 ^ 1;

  if (t == 0) {
    for (int i = tid; i < 16384; i += 256) ctxS[i] = 0.f;
  } else {
    if (tid < 128) {
      int row = tid >> 2, q = tid & 3;
      float m = -3.4e38f;
#pragma unroll
      for (int j = 0; j < 4; ++j) m = fmaxf(m, P.pM[p1 * 128 + row * 4 + j]);
      float z = 0.f;
#pragma unroll
      for (int j = 0; j < 4; ++j)
        z += P.pS[p1 * 128 + row * 4 + j] * expf(P.pM[p1 * 128 + row * 4 + j] - m);
      wqL[tid] = expf(P.pM[p1 * 128 + row * 4 + q] - m) / z;
    }
    __syncthreads();
    const float* Vb = P.V + (size_t)p1 * 65536;
    for (int i = tid; i < 16384; i += 256) {
      int row = i >> 9, c = i & 511;
      const float* v = Vb + (size_t)(row * 4) * 512 + c;
      ctxS[i] = v[0] * wqL[row * 4 + 0] + v[512] * wqL[row * 4 + 1] +
                v[1024] * wqL[row * 4 + 2] + v[1536] * wqL[row * 4 + 3];
    }
  }
  __syncthreads();

  if (blk < 128) {
    if (t < TDEC)
      gru_phase<768>((const float4*)(P.xall + (size_t)t * 8192), 64,
                     (const float4*)ctxS,
                     (const float4*)(P.ah + p1 * 16384),
                     P.Wiha, P.Whha, P.biha, P.bhha,
                     P.ah + p1 * 16384, P.ah + p0 * 16384, blk * 4, lds);
  } else {
    if (t >= 1)
      gru_phase<1024>((const float4*)(P.ah + p1 * 16384), 128,
                      (const float4*)ctxS,
                      (const float4*)(P.dh + p0 * 16384),
                      P.Wihd, P.Whhd, P.bihd, P.bhhd,
                      P.dh + p0 * 16384, P.dh + p1 * 16384, (blk - 128) * 4, lds);
  }
}

// ---- K_E: aw materialize + conv + energies + partials + V || outproj ---------
__global__ __launch_bounds__(256) void k_energy(GP P, int t) {
  __shared__ float smem[5400];
  const int tid = threadIdx.x, blk = blockIdx.x;
  const int p0 = t & 1, p1 = p0 ^ 1;

  if (blk >= 128) {  // ---- outproj(t-1) + ctx fixup, one block per row ----
    if (t < 1) return;
    const int r = blk - 128;
    float* dhcx = smem;        // [1024]
    float* opl = smem + 1024;  // 162
    float M = -3.4e38f;
#pragma unroll
    for (int j = 0; j < 4; ++j) M = fmaxf(M, P.pM[p1 * 128 + r * 4 + j]);
    float Z = 0.f;
#pragma unroll
    for (int j = 0; j < 4; ++j)
      Z += P.pS[p1 * 128 + r * 4 + j] * expf(P.pM[p1 * 128 + r * 4 + j] - M);
    float w0 = expf(P.pM[p1 * 128 + r * 4 + 0] - M) / Z;
    float w1 = expf(P.pM[p1 * 128 + r * 4 + 1] - M) / Z;
    float w2 = expf(P.pM[p1 * 128 + r * 4 + 2] - M) / Z;
    float w3 = expf(P.pM[p1 * 128 + r * 4 + 3] - M) / Z;
    const float* Vb = P.V + (size_t)p1 * 65536 + (size_t)(r * 4) * 512;
    for (int i = tid; i < 512; i += 256) {
      dhcx[i] = P.dh[p1 * 16384 + r * 512 + i];
      dhcx[512 + i] = Vb[i] * w0 + Vb[512 + i] * w1 + Vb[1024 + i] * w2 + Vb[1536 + i] * w3;
    }
    __syncthreads();
    if (tid < 162) {
      int m = tid >> 1, h = tid & 1;
      const float4* W4 = (m < 80) ? ((const float4*)P.Wout + (size_t)m * 256)
                                  : (const float4*)P.Wg;
      const float4* x4 = (const float4*)dhcx;
      float a = 0.f;
      for (int k4 = h * 128; k4 < h * 128 + 128; ++k4) a += dot4(W4[k4], x4[k4]);
      opl[tid] = a;
    }
    __syncthreads();
    if (tid < 81) {
      float sum = opl[tid * 2] + opl[tid * 2 + 1];
      if (tid < 80) P.omel[(size_t)(r * 80 + tid) * 400 + (t - 1)] = sum + P.bout[tid];
      else P.ogate[r * 400 + (t - 1)] = sum + P.bg[0];
    }
    return;
  }

  // ---- energy block: (r, q) with 75-position slice ----
  const int r = blk >> 2, q = blk & 3;
  const int pb = q * 75;
  float* awW = smem;                     // 108
  float* asW = smem + 108;               // 108
  float2* t2f = (float2*)(smem + 216);   // 992 f2 -> 1984
  float* convl = smem + 2200;            // 32*76 = 2432
  float* qpL = smem + 4632;              // 256
  float* qbL = smem + 4888;              // 128
  float* el = smem + 5016;               // 80
  float* eex = smem + 5096;              // 80

  // Phase A: materialize aw(t-1), update awsum, write oalign(t-1)
  if (t >= 1) {
    float M = -3.4e38f;
#pragma unroll
    for (int j = 0; j < 4; ++j) M = fmaxf(M, P.pM[p1 * 128 + r * 4 + j]);
    float Z = 0.f;
#pragma unroll
    for (int j = 0; j < 4; ++j)
      Z += P.pS[p1 * 128 + r * 4 + j] * expf(P.pM[p1 * 128 + r * 4 + j] - M);
    float inv = 1.f / Z;
    for (int i = tid; i < 105; i += 256) {
      int p = pb - 15 + i;
      float a = 0.f, s = 0.f;
      if (p >= 0 && p < TENC) {
        a = expf(P.e2[p1 * 9728 + r * 304 + p] - M) * inv;
        s = P.awsum2[p1 * 9600 + r * 300 + p] + a;
      }
      awW[i] = a;
      asW[i] = s;
      if (p >= pb && p < pb + 75) {
        P.awsum2[p0 * 9600 + r * 300 + p] = s;
        P.oalign[((size_t)(r * 400 + (t - 1))) * 300 + p] = a;
      }
    }
  } else {
    for (int i = tid; i < 105; i += 256) { awW[i] = 0.f; asW[i] = 0.f; }
  }
  if (t >= TDEC) return;  // t==400: only aw/oalign materialization

  for (int i = tid; i < 992; i += 256) {
    int f = i / 31, k = i % 31;
    t2f[i] = make_float2(P.Kloc[f * 62 + k], P.Kloc[f * 62 + 31 + k]);
  }
  __syncthreads();

  // conv over own 75 positions
  {
    int f = tid & 31, pl0 = tid >> 5;
    for (int pl = pl0; pl < 75; pl += 8) {
      float a = 0.f;
#pragma unroll
      for (int k = 0; k < 31; ++k) {
        float2 tv = t2f[f * 31 + k];
        a += awW[pl + k] * tv.x + asW[pl + k] * tv.y;
      }
      convl[f * 76 + pl] = a;
    }
  }
  // q-proj (redundant)
  {
    int j = tid & 127, kh = tid >> 7;
    const float4* Wq4 = (const float4*)P.Wq;
    const float4* a4 = (const float4*)(P.ah + p0 * 16384 + r * 512);
    float acc = 0.f;
    for (int k4 = kh * 64; k4 < kh * 64 + 64; ++k4) acc += dot4(Wq4[j * 128 + k4], a4[k4]);
    qpL[j * 2 + kh] = acc;
  }
  __syncthreads();
  if (tid < 128) qbL[tid] = qpL[tid * 2] + qpL[tid * 2 + 1];
  __syncthreads();
  // energies
  {
    int w = tid >> 6, lane = tid & 63;
    float wl0[32], wl1[32];
#pragma unroll
    for (int f = 0; f < 32; ++f) {
      wl0[f] = P.Wl[lane * 32 + f];
      wl1[f] = P.Wl[(lane + 64) * 32 + f];
    }
    float v0 = P.vv[lane], v1 = P.vv[lane + 64];
    float q0 = qbL[lane], q1 = qbL[64 + lane];
    int len = P.lens[r];
    for (int pl = w; pl < 75; pl += 4) {
      int p = pb + pl;
      float a0 = 0.f, a1 = 0.f;
#pragma unroll
      for (int f = 0; f < 32; ++f) {
        float c = convl[f * 76 + pl];
        a0 += c * wl0[f];
        a1 += c * wl1[f];
      }
      float e0 = tanhf(q0 + P.pmem[((size_t)r * 300 + p) * 128 + lane] + a0) * v0;
      float e1 = tanhf(q1 + P.pmem[((size_t)r * 300 + p) * 128 + 64 + lane] + a1) * v1;
      float es = e0 + e1;
#pragma unroll
      for (int off = 32; off > 0; off >>= 1) es += __shfl_xor(es, off, 64);
      if (lane == 0) {
        float ev = (p < len) ? es : -1e9f;
        P.e2[p0 * 9728 + r * 304 + p] = ev;
        el[pl] = ev;
      }
    }
  }
  __syncthreads();
  // slice max/expsum + eex (wave 0)
  if (tid < 64) {
    int lane = tid;
    float m = -3.4e38f;
    for (int i = lane; i < 75; i += 64) m = fmaxf(m, el[i]);
#pragma unroll
    for (int off = 32; off > 0; off >>= 1) m = fmaxf(m, __shfl_xor(m, off, 64));
    float s = 0.f;
    for (int i = lane; i < 75; i += 64) {
      float x = expf(el[i] - m);
      eex[i] = x;
      s += x;
    }
#pragma unroll
    for (int off = 32; off > 0; off >>= 1) s += __shfl_xor(s, off, 64);
    if (lane == 0) {
      P.pM[p0 * 128 + r * 4 + q] = m;
      P.pS[p0 * 128 + r * 4 + q] = s;
    }
  }
  __syncthreads();
  // ctx partial V_q over 512 cols (enc NT-streamed)
  {
    float* Vw = P.V + (size_t)p0 * 65536 + (size_t)(r * 4 + q) * 512;
#pragma unroll
    for (int cc = 0; cc < 2; ++cc) {
      int c = tid + cc * 256;
      float acc = 0.f;
      const float* eb = P.enc + ((size_t)(r * 300 + pb)) * 512 + c;
      for (int po = 0; po < 75; ++po) acc += eex[po] * nt_load(eb + (size_t)po * 512);
      Vw[c] = acc;
    }
  }
}

// ---- host ---------------------------------------------------------------------
extern "C" void kernel_launch(void* const* d_in, const int* in_sizes, int n_in,
                              void* d_out, int out_size, void* d_ws, size_t ws_size,
                              hipStream_t stream) {
  const float* enc = (const float*)d_in[0];
  const float* mels = (const float*)d_in[1];
  const int* lens = (const int*)d_in[2];
  const float* Wp0 = (const float*)d_in[3];
  const float* Wp1 = (const float*)d_in[4];
  const float* Wp2 = (const float*)d_in[5];

  float* ws = (float*)d_ws;
  float* x_all = ws;                    // 3,276,800
  float* pmem = x_all + 3276800;        // 1,228,800
  float* ah = pmem + 1228800;           // 2*16384 = 32,768
  float* dh = ah + 32768;               // 32,768
  float* e2 = dh + 32768;               // 2*32*304 = 19,456
  float* pM = e2 + 19456;               // 256
  float* pS = pM + 256;                 // 256
  float* V = pS + 256;                  // 2*128*512 = 131,072
  float* awsum2 = V + 131072;           // 2*9600 = 19,200

  (void)hipMemsetAsync(ah, 0, (32768 + 32768) * sizeof(float), stream);
  (void)hipMemsetAsync(awsum2, 0, 19200 * sizeof(float), stream);

  prenet_kernel<<<800, 256, 0, stream>>>(mels, Wp0, Wp1, Wp2, x_all);
  pmem_kernel<<<320, 256, 0, stream>>>(enc, (const float*)d_in[15], pmem);

  float* omel = (float*)d_out;                  // [32][80][400]
  float* ogate = omel + 32 * 80 * 400;          // [32][400]
  float* oalign = ogate + 32 * 400;             // [32][400][300]

  GP P;
  P.xall = x_all; P.enc = enc; P.pmem = pmem; P.lens = lens;
  P.Wiha = (const float*)d_in[6]; P.Whha = (const float*)d_in[7];
  P.biha = (const float*)d_in[8]; P.bhha = (const float*)d_in[9];
  P.Wihd = (const float*)d_in[10]; P.Whhd = (const float*)d_in[11];
  P.bihd = (const float*)d_in[12]; P.bhhd = (const float*)d_in[13];
  P.Wq = (const float*)d_in[14]; P.Kloc = (const float*)d_in[16];
  P.Wl = (const float*)d_in[17]; P.vv = (const float*)d_in[18];
  P.Wout = (const float*)d_in[19]; P.bout = (const float*)d_in[20];
  P.Wg = (const float*)d_in[21]; P.bg = (const float*)d_in[22];
  P.ah = ah; P.dh = dh; P.e2 = e2; P.pM = pM; P.pS = pS; P.V = V;
  P.awsum2 = awsum2;
  P.omel = omel; P.ogate = ogate; P.oalign = oalign;

  for (int t = 0; t <= TDEC; ++t) {
    k_gru<<<256, 256, 0, stream>>>(P, t);
    k_energy<<<160, 256, 0, stream>>>(P, t);
  }
}